// Round 6
// baseline (167.515 us; speedup 1.0000x reference)
//
#include <hip/hip_runtime.h>

#define B_    32
#define CIN_  64
#define COUT_ 64
#define IMG_  128
#define W4_   32                 // float4 per row
#define PIX4_ 4096               // float4 per plane
#define NPOS_ (B_ * PIX4_)       // 131072 float4 positions
#define REP_  4                  // DIAGNOSTIC: repeat factor (idempotent)

// ---- Kernel A (diag, 4x repeat): partial channel sums, quasi-sequential.
// Block n -> (b, g, q): reads 32 channels x 8 KiB contiguous chunk, c-loop
// unroll 8 with 2 positions/thread => 16 float4 loads in flight. ----
__global__ __launch_bounds__(256) void ch_sum_diag(const float* __restrict__ x,
                                                   float* __restrict__ part) {
    const int n   = blockIdx.x;          // 0..511
    const int q   = n & 7;               // eighth-of-plane chunk
    const int g   = (n >> 3) & 1;        // channel group
    const int b   = n >> 4;              // batch
    const int tid = threadIdx.x;
    const int off0 = q * 512 + tid;
    const int off1 = off0 + 256;

    const float4* xp = reinterpret_cast<const float4*>(x)
                     + ((size_t)b * CIN_ + (size_t)g * 32) * PIX4_;
    float4* pp = reinterpret_cast<float4*>(part)
               + (size_t)g * NPOS_ + (size_t)b * PIX4_;

    for (int rep = 0; rep < REP_; ++rep) {
        float4 a0 = make_float4(0.f, 0.f, 0.f, 0.f);
        float4 a1 = make_float4(0.f, 0.f, 0.f, 0.f);
#pragma unroll 8
        for (int c = 0; c < 32; ++c) {
            float4 v0 = xp[(size_t)c * PIX4_ + off0];
            float4 v1 = xp[(size_t)c * PIX4_ + off1];
            a0.x += v0.x; a0.y += v0.y; a0.z += v0.z; a0.w += v0.w;
            a1.x += v1.x; a1.y += v1.y; a1.z += v1.z; a1.w += v1.w;
        }
        pp[off0] = a0;
        pp[off1] = a1;
        asm volatile("" ::: "memory");   // force re-execution per rep
    }
}

// ---- Kernel B (diag, 4x repeat): block = (b, co, half-plane). Stage 66 rows
// (sum of the 2 partial planes) in LDS; thread computes 8 consecutive rows at
// fixed w4 via sliding 3-row window; stores walk the plane sequentially. ----
__global__ __launch_bounds__(256, 4) void conv_plane_diag(const float* __restrict__ part,
                                                          const float* __restrict__ kern,
                                                          const float* __restrict__ bias,
                                                          float* __restrict__ out) {
    __shared__ float t[66 * IMG_];                    // 33 KB

    const int n   = blockIdx.x;                       // 0..4095
    const int swz = (n & 7) * 512 + (n >> 3);         // bijective XCD chunking
    const int co   = swz & 63;
    const int half = (swz >> 6) & 1;
    const int b    = swz >> 7;
    const int tid  = threadIdx.x;
    const int r0   = half * 64;

    const float4* p0 = reinterpret_cast<const float4*>(part) + (size_t)b * PIX4_;
    const float4* p1 = p0 + (size_t)NPOS_;

    const float* kw = kern + co * 9;
    const float k0 = kw[0], k1 = kw[1], k2 = kw[2];
    const float k3 = kw[3], k4 = kw[4], k5 = kw[5];
    const float k6 = kw[6], k7 = kw[7], k8 = kw[8];
    const float bv = (float)CIN_ * bias[co];

    const int w4 = tid & 31;
    const int rb = (tid >> 5) * 8;                    // local output rows rb..rb+7
    float4* outp = reinterpret_cast<float4*>(out) + (size_t)(b * COUT_ + co) * PIX4_;
    const float4* tp = reinterpret_cast<const float4*>(t);
    const float4 z4 = make_float4(0.f, 0.f, 0.f, 0.f);

    for (int rep = 0; rep < REP_; ++rep) {
        __syncthreads();                              // quiesce before re-stage
        for (int pos = tid; pos < 66 * W4_; pos += 256) {
            const int lr  = pos >> 5;
            const int w4s = pos & 31;
            const int row = r0 - 1 + lr;
            float4 v = z4;
            if (row >= 0 && row < IMG_) {
                float4 u0 = p0[row * W4_ + w4s];
                float4 u1 = p1[row * W4_ + w4s];
                v = make_float4(u0.x + u1.x, u0.y + u1.y, u0.z + u1.z, u0.w + u1.w);
            }
            reinterpret_cast<float4*>(t)[pos] = v;
        }
        __syncthreads();

        float4 L[3], C[3], R[3];
#define LOAD3(slot, tr)                                                        \
        do {                                                                   \
            const float4* rowp = tp + (tr) * W4_;                              \
            C[slot] = rowp[w4];                                                \
            L[slot] = (w4 > 0)  ? rowp[w4 - 1] : z4;                           \
            R[slot] = (w4 < 31) ? rowp[w4 + 1] : z4;                           \
        } while (0)

        LOAD3(0, rb + 0);
        LOAD3(1, rb + 1);

#pragma unroll
        for (int j = 0; j < 8; ++j) {
            LOAD3((j + 2) % 3, rb + j + 2);
            const int st = j % 3, sm = (j + 1) % 3, sb = (j + 2) % 3;
            float4 a;
            a.x = bv + k0 * L[st].w + k1 * C[st].x + k2 * C[st].y
                     + k3 * L[sm].w + k4 * C[sm].x + k5 * C[sm].y
                     + k6 * L[sb].w + k7 * C[sb].x + k8 * C[sb].y;
            a.y = bv + k0 * C[st].x + k1 * C[st].y + k2 * C[st].z
                     + k3 * C[sm].x + k4 * C[sm].y + k5 * C[sm].z
                     + k6 * C[sb].x + k7 * C[sb].y + k8 * C[sb].z;
            a.z = bv + k0 * C[st].y + k1 * C[st].z + k2 * C[st].w
                     + k3 * C[sm].y + k4 * C[sm].z + k5 * C[sm].w
                     + k6 * C[sb].y + k7 * C[sb].z + k8 * C[sb].w;
            a.w = bv + k0 * C[st].z + k1 * C[st].w + k2 * R[st].x
                     + k3 * C[sm].z + k4 * C[sm].w + k5 * R[sm].x
                     + k6 * C[sb].z + k7 * C[sb].w + k8 * R[sb].x;
            outp[(size_t)(r0 + rb + j) * W4_ + w4] = a;
        }
#undef LOAD3
        asm volatile("" ::: "memory");
    }
}

extern "C" void kernel_launch(void* const* d_in, const int* in_sizes, int n_in,
                              void* d_out, int out_size, void* d_ws, size_t ws_size,
                              hipStream_t stream) {
    const float* x    = (const float*)d_in[0];   // (32,64,128,128) f32
    const float* kern = (const float*)d_in[1];   // (64,3,3) f32
    const float* bias = (const float*)d_in[2];   // (64,1,1,1) f32
    float* out  = (float*)d_out;                 // (32,64,128,128) f32
    float* part = (float*)d_ws;                  // 2 x 2 MiB partial planes

    ch_sum_diag<<<dim3(512), 256, 0, stream>>>(x, part);
    conv_plane_diag<<<dim3(B_ * COUT_ * 2), 256, 0, stream>>>(part, kern, bias, out);
}

// Round 7
// 60.167 us; speedup vs baseline: 2.7842x; 2.7842x over previous
//
#include <hip/hip_runtime.h>

#define B_    32
#define CIN_  64
#define COUT_ 64
#define IMG_  128
#define W4_   32                 // float4 per row
#define PIX4_ 4096               // float4 per plane
#define NPOS_ (B_ * PIX4_)       // 131072 float4 positions

// ---- Kernel A: 2-group partial channel sums (512 blocks). Reads 134 MB
// (partially L3-resident across replays), writes 8 MB of partials. ----
__global__ __launch_bounds__(256) void ch_sum2(const float* __restrict__ x,
                                               float* __restrict__ part) {
    const int g   = blockIdx.y;                    // 0..1 channel group
    const int tid = threadIdx.x;
    const int i0  = blockIdx.x * 512 + tid;        // chunk of 512 float4
    const int i1  = i0 + 256;
    const int b   = i0 >> 12;
    const int p0  = i0 & (PIX4_ - 1);

    const float4* xp = reinterpret_cast<const float4*>(x)
                     + ((size_t)b * CIN_ + (size_t)g * 32) * PIX4_ + p0;

    float4 a0 = make_float4(0.f, 0.f, 0.f, 0.f);
    float4 a1 = make_float4(0.f, 0.f, 0.f, 0.f);
#pragma unroll 8
    for (int c = 0; c < 32; ++c) {
        float4 v0 = xp[(size_t)c * PIX4_];
        float4 v1 = xp[(size_t)c * PIX4_ + 256];
        a0.x += v0.x; a0.y += v0.y; a0.z += v0.z; a0.w += v0.w;
        a1.x += v1.x; a1.y += v1.y; a1.z += v1.z; a1.w += v1.w;
    }
    float4* pp = reinterpret_cast<float4*>(part) + (size_t)g * NPOS_;
    pp[i0] = a0;
    pp[i1] = a1;
}

// ---- Kernel B: no LDS. Block = (b, co, half-plane). Each thread owns 8
// consecutive rows at fixed w4: loads its 10-row float4 column from the two
// L2-resident partial planes (20 coalesced b128 loads), halo scalars via
// shfl, streams 8 sequential float4 stores. ----
__global__ __launch_bounds__(256) void conv_shfl(const float* __restrict__ part,
                                                 const float* __restrict__ kern,
                                                 const float* __restrict__ bias,
                                                 float* __restrict__ out) {
    const int n   = blockIdx.x;                    // 0..4095
    const int swz = (n & 7) * 512 + (n >> 3);      // bijective XCD chunking
    const int co   = swz & 63;
    const int half = (swz >> 6) & 1;
    const int b    = swz >> 7;
    const int tid  = threadIdx.x;
    const int w4   = tid & 31;
    const int rb   = (tid >> 5) * 8;               // local output rows rb..rb+7
    const int r0   = half * 64;

    const float4* p0 = reinterpret_cast<const float4*>(part) + (size_t)b * PIX4_;
    const float4* p1 = p0 + (size_t)NPOS_;

    // 10-row column of summed partials (C), all loads issued up front.
    float4 C[10];
#pragma unroll
    for (int r = 0; r < 10; ++r) {
        const int row = r0 + rb - 1 + r;
        float4 v = make_float4(0.f, 0.f, 0.f, 0.f);
        if (row >= 0 && row < IMG_) {
            float4 u0 = p0[row * W4_ + w4];
            float4 u1 = p1[row * W4_ + w4];
            v = make_float4(u0.x + u1.x, u0.y + u1.y, u0.z + u1.z, u0.w + u1.w);
        }
        C[r] = v;
    }

    // Halo scalars from neighbors (32-lane segments = one w4 row group).
    float Lw[10], Rx[10];
#pragma unroll
    for (int r = 0; r < 10; ++r) {
        float lw = __shfl_up(C[r].w, 1, 32);
        float rx = __shfl_down(C[r].x, 1, 32);
        Lw[r] = (w4 > 0)  ? lw : 0.f;
        Rx[r] = (w4 < 31) ? rx : 0.f;
    }

    const float* kw = kern + co * 9;
    const float k0 = kw[0], k1 = kw[1], k2 = kw[2];
    const float k3 = kw[3], k4 = kw[4], k5 = kw[5];
    const float k6 = kw[6], k7 = kw[7], k8 = kw[8];
    const float bv = (float)CIN_ * bias[co];

    float4* outp = reinterpret_cast<float4*>(out) + (size_t)(b * COUT_ + co) * PIX4_;

#pragma unroll
    for (int j = 0; j < 8; ++j) {                  // rows j, j+1, j+2 of C
        float4 a;
        a.x = bv + k0 * Lw[j]     + k1 * C[j].x     + k2 * C[j].y
                 + k3 * Lw[j + 1] + k4 * C[j + 1].x + k5 * C[j + 1].y
                 + k6 * Lw[j + 2] + k7 * C[j + 2].x + k8 * C[j + 2].y;
        a.y = bv + k0 * C[j].x     + k1 * C[j].y     + k2 * C[j].z
                 + k3 * C[j + 1].x + k4 * C[j + 1].y + k5 * C[j + 1].z
                 + k6 * C[j + 2].x + k7 * C[j + 2].y + k8 * C[j + 2].z;
        a.z = bv + k0 * C[j].y     + k1 * C[j].z     + k2 * C[j].w
                 + k3 * C[j + 1].y + k4 * C[j + 1].z + k5 * C[j + 1].w
                 + k6 * C[j + 2].y + k7 * C[j + 2].z + k8 * C[j + 2].w;
        a.w = bv + k0 * C[j].z     + k1 * C[j].w     + k2 * Rx[j]
                 + k3 * C[j + 1].z + k4 * C[j + 1].w + k5 * Rx[j + 1]
                 + k6 * C[j + 2].z + k7 * C[j + 2].w + k8 * Rx[j + 2];
        outp[(size_t)(r0 + rb + j) * W4_ + w4] = a;
    }
}

extern "C" void kernel_launch(void* const* d_in, const int* in_sizes, int n_in,
                              void* d_out, int out_size, void* d_ws, size_t ws_size,
                              hipStream_t stream) {
    const float* x    = (const float*)d_in[0];   // (32,64,128,128) f32
    const float* kern = (const float*)d_in[1];   // (64,3,3) f32
    const float* bias = (const float*)d_in[2];   // (64,1,1,1) f32
    float* out  = (float*)d_out;                 // (32,64,128,128) f32
    float* part = (float*)d_ws;                  // 2 x 2 MiB partial planes

    dim3 ga(NPOS_ / 512, 2);                     // (256, 2) = 512 blocks
    ch_sum2<<<ga, 256, 0, stream>>>(x, part);

    conv_shfl<<<dim3(B_ * COUT_ * 2), 256, 0, stream>>>(part, kern, bias, out);
}